// Round 13
// baseline (102.583 us; speedup 1.0000x reference)
//
#include <hip/hip_runtime.h>

// RNN: h_t = tanh(x_t*w_ih + b_ih + b_hh + W_hh h_{t-1});  out = h_T . w_fc + b_fc
// B=4096, T=512, I=1, H=16, O=1.
//
// Round 10: attack the unhidden serial TAIL (r5 vs r9 both 112 cyc/step,
// VALUBusy 48% -> issue 54 + tail ~58).
//  * Reduction tree moved INTO the asm block (6 v_add_f32 after the fmacs):
//    overlaps add latency with fmac issue; removes the compiler's
//    wait-for-all-asm-outputs serialization.
//  * Split-exp: 2^(ha+hb) = 2^ha * 2^hb, r = rcp(fma(Ea,Eb,1)).
//    Two independent exps (parallel trans pipe); +1 merged into fma.
//    Post-asm tail: exp -> fma -> rcp (3 levels) vs add*3 -> exp -> add -> rcp.
// Everything else identical to r9 (verified PASS, absmax 1.9e-6):
//  16-lane layout, r-state fold (r = 1/(exp2(s')+1), h = 1-2r in weights,
//  rowsum in bias), direction-proof DPP weight gather (ctrl 0x120+r matches
//  the asm's row_ror:r), fused v_mul/fmac_f32_dpp ladder, s_nop hazard guard.

constexpr int T_STEPS = 512;
constexpr float C2LE = 2.8853900817779268f; // 2*log2(e)

#define DPP_CTRL_ROR(r) (0x120 + (r))
#define DPP_ROR_IDX(r, src) __builtin_amdgcn_update_dpp(0, (src), DPP_CTRL_ROR(r), 0xF, 0xF, false)

__global__ __launch_bounds__(256) void rnn_fused(
    const float* __restrict__ x,
    const float* __restrict__ w_ih,
    const float* __restrict__ w_hh,
    const float* __restrict__ b_ih,
    const float* __restrict__ b_hh,
    const float* __restrict__ w_fc,
    const float* __restrict__ b_fc,
    float* __restrict__ out)
{
    const int tid = blockIdx.x * blockDim.x + threadIdx.x;
    const int b   = tid >> 4;   // batch element (16 lanes each)
    const int me  = tid & 15;   // hidden unit owned by this lane

    // Bias carries the h = 1-2r constant part: full 16-term rowsum.
    float rowsum = 0.0f;
    {
        const int base = me << 4;
        #pragma unroll
        for (int k = 0; k < 16; ++k) rowsum += w_hh[base + k];
    }
    const float wihc  = w_ih[me] * C2LE;
    const float biasc = (b_ih[me] + b_hh[me] + rowsum) * C2LE;

    // Direction-proof weight gather; scale by -2*C2LE (the -2r fold).
    const float WS = -2.0f * C2LE;
    float wr[16];
    {
        const int base = me << 4;            // w_hh row 'me' (H x H row-major)
        wr[0] = w_hh[base + me] * WS;
        #define WSETUP(r) { int s_ = DPP_ROR_IDX(r, me); wr[r] = w_hh[base + s_] * WS; }
        WSETUP(1)  WSETUP(2)  WSETUP(3)  WSETUP(4)  WSETUP(5)
        WSETUP(6)  WSETUP(7)  WSETUP(8)  WSETUP(9)  WSETUP(10)
        WSETUP(11) WSETUP(12) WSETUP(13) WSETUP(14) WSETUP(15)
        #undef WSETUP
    }
    const float w0 = wr[0],  w1 = wr[1],  w2 = wr[2],  w3 = wr[3];
    const float w4 = wr[4],  w5 = wr[5],  w6 = wr[6],  w7 = wr[7];
    const float w8 = wr[8],  w9 = wr[9],  w10 = wr[10], w11 = wr[11];
    const float w12 = wr[12], w13 = wr[13], w14 = wr[14], w15 = wr[15];

    const float* xb = x + ((size_t)b << 9);  // x[b,:,0], 512 floats, 16B aligned
    float r_ = 0.5f;                         // h0 = 0 -> r0 = 0.5

    // One timestep: ladder (7 mul_dpp + 8 fmac_dpp) + in-asm 2-half tree;
    // outputs ha (A0, incl. seeds) and hb (A4). Tail: 2 parallel exp2 ->
    // fma(+1) -> rcp. ~27 issued VALU, post-asm chain only 3 levels.
    #define STEP(xval) {                                                        \
        float A0 = fmaf((xval), wihc, biasc);                                   \
        A0 = fmaf(r_, w0, A0);                                                  \
        float A1, A2, A3, A4, A5, A6, A7;                                       \
        asm volatile(                                                           \
          "s_nop 1\n\t"                                                         \
          "v_mul_f32_dpp  %1, %8, %10 row_ror:1 row_mask:0xf bank_mask:0xf\n\t" \
          "v_mul_f32_dpp  %2, %8, %11 row_ror:2 row_mask:0xf bank_mask:0xf\n\t" \
          "v_mul_f32_dpp  %3, %8, %12 row_ror:3 row_mask:0xf bank_mask:0xf\n\t" \
          "v_mul_f32_dpp  %4, %8, %13 row_ror:4 row_mask:0xf bank_mask:0xf\n\t" \
          "v_mul_f32_dpp  %5, %8, %14 row_ror:5 row_mask:0xf bank_mask:0xf\n\t" \
          "v_mul_f32_dpp  %6, %8, %15 row_ror:6 row_mask:0xf bank_mask:0xf\n\t" \
          "v_mul_f32_dpp  %7, %8, %16 row_ror:7 row_mask:0xf bank_mask:0xf\n\t" \
          "v_fmac_f32_dpp %0, %8, %17 row_ror:8 row_mask:0xf bank_mask:0xf\n\t" \
          "v_fmac_f32_dpp %1, %8, %18 row_ror:9 row_mask:0xf bank_mask:0xf\n\t" \
          "v_fmac_f32_dpp %2, %8, %19 row_ror:10 row_mask:0xf bank_mask:0xf\n\t"\
          "v_fmac_f32_dpp %3, %8, %20 row_ror:11 row_mask:0xf bank_mask:0xf\n\t"\
          "v_fmac_f32_dpp %4, %8, %21 row_ror:12 row_mask:0xf bank_mask:0xf\n\t"\
          "v_fmac_f32_dpp %5, %8, %22 row_ror:13 row_mask:0xf bank_mask:0xf\n\t"\
          "v_fmac_f32_dpp %6, %8, %23 row_ror:14 row_mask:0xf bank_mask:0xf\n\t"\
          "v_fmac_f32_dpp %7, %8, %24 row_ror:15 row_mask:0xf bank_mask:0xf\n\t"\
          "v_add_f32 %0, %0, %1\n\t"  /* A0+A1            */                    \
          "v_add_f32 %2, %2, %3\n\t"  /* A2+A3            */                    \
          "v_add_f32 %4, %4, %5\n\t"  /* A4+A5            */                    \
          "v_add_f32 %6, %6, %7\n\t"  /* A6+A7            */                    \
          "v_add_f32 %0, %0, %2\n\t"  /* ha = A0..A3+seeds */                   \
          "v_add_f32 %4, %4, %6"      /* hb = A4..A7       */                   \
          : "+v"(A0), "=&v"(A1), "=&v"(A2), "=&v"(A3),                          \
            "=&v"(A4), "=&v"(A5), "=&v"(A6), "=&v"(A7)                          \
          : "v"(r_), "v"(w0) /* %9 unused, keeps numbering */,                  \
            "v"(w1), "v"(w2), "v"(w3), "v"(w4), "v"(w5), "v"(w6), "v"(w7),      \
            "v"(w8), "v"(w9), "v"(w10), "v"(w11), "v"(w12), "v"(w13),           \
            "v"(w14), "v"(w15));                                                \
        const float Ea = __builtin_amdgcn_exp2f(A0);                            \
        const float Eb = __builtin_amdgcn_exp2f(A4);                            \
        r_ = __builtin_amdgcn_rcpf(fmaf(Ea, Eb, 1.0f)); /* r = 1/(1+2^s) */     \
    }

    // 8 steps/iter; next x block prefetched as 2x float4 (L1-resident,
    // 16 lanes same address -> broadcast).
    float4 cur0 = *reinterpret_cast<const float4*>(xb);
    float4 cur1 = *reinterpret_cast<const float4*>(xb + 4);
    #pragma unroll 1
    for (int tb = 0; tb < T_STEPS; tb += 8) {
        const int nxt = (tb + 8 < T_STEPS) ? (tb + 8) : 0;  // last iter: dummy
        const float4 n0 = *reinterpret_cast<const float4*>(xb + nxt);
        const float4 n1 = *reinterpret_cast<const float4*>(xb + nxt + 4);
        STEP(cur0.x) STEP(cur0.y) STEP(cur0.z) STEP(cur0.w)
        STEP(cur1.x) STEP(cur1.y) STEP(cur1.z) STEP(cur1.w)
        cur0 = n0; cur1 = n1;
    }
    #undef STEP

    // Reconstruct h = 1 - 2r once; out[b] = dot(h, w_fc) + b_fc.
    const float h = fmaf(-2.0f, r_, 1.0f);
    float v = h * w_fc[me];
    v += __shfl_xor(v, 8);
    v += __shfl_xor(v, 4);
    v += __shfl_xor(v, 2);
    v += __shfl_xor(v, 1);
    if (me == 0) out[b] = v + b_fc[0];
}

extern "C" void kernel_launch(void* const* d_in, const int* in_sizes, int n_in,
                              void* d_out, int out_size, void* d_ws, size_t ws_size,
                              hipStream_t stream) {
    const float* x    = (const float*)d_in[0];
    const float* w_ih = (const float*)d_in[1];
    const float* w_hh = (const float*)d_in[2];
    const float* b_ih = (const float*)d_in[3];
    const float* b_hh = (const float*)d_in[4];
    const float* w_fc = (const float*)d_in[5];
    const float* b_fc = (const float*)d_in[6];
    float* out = (float*)d_out;

    const int B = out_size;                  // 4096
    const int threads = 256;
    const int blocks  = (B * 16) / threads;  // 256 blocks -> 1/CU, 1 wave/SIMD
    rnn_fused<<<blocks, threads, 0, stream>>>(x, w_ih, w_hh, b_ih, b_hh, w_fc, b_fc, out);
}